// Round 1
// baseline (237.298 us; speedup 1.0000x reference)
//
#include <hip/hip_runtime.h>
#include <hip/hip_fp16.h>
#include <math.h>

typedef _Float16 half8  __attribute__((ext_vector_type(8)));
typedef _Float16 half2v __attribute__((ext_vector_type(2)));
typedef float   floatx4 __attribute__((ext_vector_type(4)));

#define ROWS   16384
#define DIM    128
#define KCODES 8192
#define NSPLIT 8
#define MTILE  128
#define NT     64

// ---------------- kernel 1: codebook prep (fp16 hi/lo split + e2) ----------------
__global__ __launch_bounds__(256) void prep_codebook(
    const float* __restrict__ cb, _Float16* __restrict__ ehg,
    _Float16* __restrict__ elg, float* __restrict__ e2g)
{
  int tid = threadIdx.x;
  int L = tid & 63;
  int row = blockIdx.x * 4 + (tid >> 6);
  const float2* cr = (const float2*)(cb + (size_t)row * DIM);
  float2 v = cr[L];
  float s2 = v.x * v.x + v.y * v.y;
  #pragma unroll
  for (int m = 1; m < 64; m <<= 1) s2 += __shfl_xor(s2, m);
  if (L == 0) e2g[row] = s2;
  _Float16 h0 = (_Float16)v.x, h1 = (_Float16)v.y;
  half2v hi = {h0, h1};
  half2v lo = {(_Float16)(v.x - (float)h0), (_Float16)(v.y - (float)h1)};
  ((half2v*)(ehg + (size_t)row * DIM))[L] = hi;
  ((half2v*)(elg + (size_t)row * DIM))[L] = lo;
}

// ---------------- kernel 2: LN + distance argmin via split-fp16 MFMA ----------------
// block = 256 thr = 4 waves; wave handles 32 rows (2 groups of 16).
// grid = (ROWS/MTILE) * NSPLIT; each block scans KCODES/NSPLIT codes in chunks of NT.
__global__ __launch_bounds__(256, 2) void argmin_kernel(
    const float* __restrict__ x, const _Float16* __restrict__ ehg,
    const _Float16* __restrict__ elg, const float* __restrict__ e2g,
    float* __restrict__ best_part, int* __restrict__ idx_part)
{
  // [64][136]: pad 128->136 halfs keeps 16B alignment and uniform bank spread
  __shared__ _Float16 eh[64][136];
  __shared__ _Float16 el[64][136];
  __shared__ float e2s[64];

  int tid = threadIdx.x;
  int w   = tid >> 6;
  int L   = tid & 63;
  int c   = L & 15;      // MFMA A-row / D-col lane index
  int q   = L >> 4;      // quad

  int bx = blockIdx.x;
  int mt = bx & (ROWS / MTILE - 1);
  int ns = bx >> 7;      // log2(ROWS/MTILE) = 7

  int rowbase = mt * MTILE + w * 32;

  half8 ah[2][4], al[2][4];
  float x2b[2][4];

  #pragma unroll
  for (int g = 0; g < 2; ++g) {
    const float* xr = x + (size_t)(rowbase + g * 16 + c) * DIM;
    float v[32];
    #pragma unroll
    for (int ks = 0; ks < 4; ++ks) {
      float4 p0 = *(const float4*)(xr + ks * 32 + q * 8);
      float4 p1 = *(const float4*)(xr + ks * 32 + q * 8 + 4);
      v[ks*8+0] = p0.x; v[ks*8+1] = p0.y; v[ks*8+2] = p0.z; v[ks*8+3] = p0.w;
      v[ks*8+4] = p1.x; v[ks*8+5] = p1.y; v[ks*8+6] = p1.z; v[ks*8+7] = p1.w;
    }
    // LayerNorm over the row (two-pass, matches reference formula)
    float s = 0.f;
    #pragma unroll
    for (int i = 0; i < 32; ++i) s += v[i];
    s += __shfl_xor(s, 16); s += __shfl_xor(s, 32);
    float mu = s * (1.0f / 128.0f);
    float s2 = 0.f;
    #pragma unroll
    for (int i = 0; i < 32; ++i) { float d = v[i] - mu; s2 += d * d; }
    s2 += __shfl_xor(s2, 16); s2 += __shfl_xor(s2, 32);
    float rstd = 1.0f / sqrtf(s2 * (1.0f / 128.0f) + 1e-5f);
    float x2 = 0.f;
    #pragma unroll
    for (int i = 0; i < 32; ++i) { float xn = (v[i] - mu) * rstd; v[i] = xn; x2 += xn * xn; }
    x2 += __shfl_xor(x2, 16); x2 += __shfl_xor(x2, 32);
    // split to fp16 hi/lo, pack A-frags: lane holds A[m=lane&15][k=quad*8+j]
    #pragma unroll
    for (int ks = 0; ks < 4; ++ks)
      #pragma unroll
      for (int j = 0; j < 8; ++j) {
        float xv = v[ks*8+j];
        _Float16 h = (_Float16)xv;
        ah[g][ks][j] = h;
        al[g][ks][j] = (_Float16)(xv - (float)h);
      }
    // x2 lives in lanes keyed by (L&15); D-layout needs row = quad*4+r
    #pragma unroll
    for (int r = 0; r < 4; ++r) x2b[g][r] = __shfl(x2, q * 4 + r);
  }

  float best[2][4]; int bidx[2][4];
  #pragma unroll
  for (int g = 0; g < 2; ++g)
    #pragma unroll
    for (int r = 0; r < 4; ++r) { best[g][r] = 3.4e38f; bidx[g][r] = 0; }

  int code0 = ns * (KCODES / NSPLIT);
  for (int ch = 0; ch < (KCODES / NSPLIT) / NT; ++ch) {
    int cbase = code0 + ch * NT;
    __syncthreads();
    // stage 64-code hi/lo tiles (each contiguous 16 KB in global)
    #pragma unroll
    for (int it = 0; it < 4; ++it) {
      int cid = it * 256 + tid;          // 0..1023 chunks of 8 halfs
      int n = cid >> 4, kc = cid & 15;
      *(uint4*)&eh[n][kc * 8] = ((const uint4*)(ehg + (size_t)(cbase + n) * DIM))[kc];
      *(uint4*)&el[n][kc * 8] = ((const uint4*)(elg + (size_t)(cbase + n) * DIM))[kc];
    }
    if (tid < 64) e2s[tid] = e2g[cbase + tid];
    __syncthreads();

    #pragma unroll
    for (int s = 0; s < 4; ++s) {        // 4 n-subtiles of 16 codes
      half8 bh[4], bl[4];
      #pragma unroll
      for (int ks = 0; ks < 4; ++ks) {
        bh[ks] = *(const half8*)&eh[s * 16 + c][ks * 32 + q * 8];
        bl[ks] = *(const half8*)&el[s * 16 + c][ks * 32 + q * 8];
      }
      float e2v = e2s[s * 16 + c];
      int n = cbase + s * 16 + c;
      #pragma unroll
      for (int g = 0; g < 2; ++g) {
        floatx4 acc = {0.f, 0.f, 0.f, 0.f};
        #pragma unroll
        for (int ks = 0; ks < 4; ++ks) {
          acc = __builtin_amdgcn_mfma_f32_16x16x32_f16(ah[g][ks], bh[ks], acc, 0, 0, 0);
          acc = __builtin_amdgcn_mfma_f32_16x16x32_f16(ah[g][ks], bl[ks], acc, 0, 0, 0);
          acc = __builtin_amdgcn_mfma_f32_16x16x32_f16(al[g][ks], bh[ks], acc, 0, 0, 0);
        }
        #pragma unroll
        for (int r = 0; r < 4; ++r) {
          float dist = (x2b[g][r] - 2.0f * acc[r]) + e2v;
          if (dist < best[g][r]) { best[g][r] = dist; bidx[g][r] = n; }
        }
      }
    }
  }

  // reduce over the 16 col-lanes of each quad; ties -> smaller index (np.argmin)
  #pragma unroll
  for (int m = 1; m < 16; m <<= 1)
    #pragma unroll
    for (int g = 0; g < 2; ++g)
      #pragma unroll
      for (int r = 0; r < 4; ++r) {
        float ob = __shfl_xor(best[g][r], m);
        int   oi = __shfl_xor(bidx[g][r], m);
        if (ob < best[g][r] || (ob == best[g][r] && oi < bidx[g][r])) {
          best[g][r] = ob; bidx[g][r] = oi;
        }
      }
  if (c == 0) {
    #pragma unroll
    for (int g = 0; g < 2; ++g)
      #pragma unroll
      for (int r = 0; r < 4; ++r) {
        int row = rowbase + g * 16 + q * 4 + r;
        best_part[(size_t)row * NSPLIT + ns] = best[g][r];
        idx_part [(size_t)row * NSPLIT + ns] = bidx[g][r];
      }
  }
}

// ---------------- kernel 3: merge N-splits ----------------
__global__ __launch_bounds__(256) void merge_kernel(
    const float* __restrict__ best_part, const int* __restrict__ idx_part,
    float* __restrict__ out_ind, int* __restrict__ ws_idx)
{
  int row = blockIdx.x * 256 + threadIdx.x;
  float b = 3.4e38f; int bi = 0;
  #pragma unroll
  for (int s = 0; s < NSPLIT; ++s) {
    float d = best_part[(size_t)row * NSPLIT + s];
    int   i = idx_part [(size_t)row * NSPLIT + s];
    if (d < b || (d == b && i < bi)) { b = d; bi = i; }
  }
  out_ind[row] = (float)bi;
  ws_idx[row] = bi;
}

// ---------------- kernel 4: gather codebook rows + per-row loss ----------------
__global__ __launch_bounds__(256) void gather_loss_kernel(
    const float* __restrict__ x, const float* __restrict__ cb,
    const int* __restrict__ ws_idx, float* __restrict__ out_q,
    float* __restrict__ row_loss)
{
  int tid = threadIdx.x;
  int L = tid & 63;
  int row = blockIdx.x * 4 + (tid >> 6);
  int idx = ws_idx[row];
  float2 qv = ((const float2*)(cb + (size_t)idx * DIM))[L];
  float2 xv = ((const float2*)(x  + (size_t)row * DIM))[L];
  float s = xv.x + xv.y;
  #pragma unroll
  for (int m = 1; m < 64; m <<= 1) s += __shfl_xor(s, m);
  float mu = s * (1.0f / 128.0f);
  float dx = xv.x - mu, dy = xv.y - mu;
  float s2 = dx * dx + dy * dy;
  #pragma unroll
  for (int m = 1; m < 64; m <<= 1) s2 += __shfl_xor(s2, m);
  float rstd = 1.0f / sqrtf(s2 * (1.0f / 128.0f) + 1e-5f);
  float xn0 = dx * rstd, xn1 = dy * rstd;
  ((float2*)out_q)[(size_t)row * 64 + L] = qv;   // quantize_st forward value == codebook row
  float e0 = qv.x - xn0, e1 = qv.y - xn1;
  float le = e0 * e0 + e1 * e1;
  #pragma unroll
  for (int m = 1; m < 64; m <<= 1) le += __shfl_xor(le, m);
  if (L == 0) row_loss[row] = le;
}

// ---------------- kernel 5: deterministic loss reduction ----------------
__global__ __launch_bounds__(256) void loss_reduce_kernel(
    const float* __restrict__ row_loss, float* __restrict__ out_loss)
{
  __shared__ float sm[256];
  int tid = threadIdx.x;
  float s = 0.f;
  for (int i = tid; i < ROWS; i += 256) s += row_loss[i];
  sm[tid] = s; __syncthreads();
  for (int st = 128; st > 0; st >>= 1) {
    if (tid < st) sm[tid] += sm[tid + st];
    __syncthreads();
  }
  if (tid == 0) *out_loss = sm[0] * (1.0f / (float)(ROWS * DIM));
}

extern "C" void kernel_launch(void* const* d_in, const int* in_sizes, int n_in,
                              void* d_out, int out_size, void* d_ws, size_t ws_size,
                              hipStream_t stream)
{
  const float* x  = (const float*)d_in[0];   // [4,4096,128] fp32
  const float* cb = (const float*)d_in[1];   // [8192,128]  fp32

  char* ws = (char*)d_ws;
  _Float16* ehg      = (_Float16*)(ws + 0);          // 2 MB
  _Float16* elg      = (_Float16*)(ws + 2097152);    // 2 MB
  float*    e2g      = (float*)   (ws + 4194304);    // 32 KB
  float*    best_part= (float*)   (ws + 4227072);    // 512 KB
  int*      idx_part = (int*)     (ws + 4751360);    // 512 KB
  int*      ws_idx   = (int*)     (ws + 5275648);    // 64 KB
  float*    row_loss = (float*)   (ws + 5341184);    // 64 KB

  float* out_q    = (float*)d_out;                   // 16384*128
  float* out_ind  = out_q + (size_t)ROWS * DIM;      // 16384 (as float)
  float* out_loss = out_ind + ROWS;                  // 1

  prep_codebook<<<KCODES / 4, 256, 0, stream>>>(cb, ehg, elg, e2g);
  argmin_kernel<<<(ROWS / MTILE) * NSPLIT, 256, 0, stream>>>(x, ehg, elg, e2g, best_part, idx_part);
  merge_kernel<<<ROWS / 256, 256, 0, stream>>>(best_part, idx_part, out_ind, ws_idx);
  gather_loss_kernel<<<ROWS / 4, 256, 0, stream>>>(x, cb, ws_idx, out_q, row_loss);
  loss_reduce_kernel<<<1, 256, 0, stream>>>(row_loss, out_loss);
}